// Round 1
// baseline (329.732 us; speedup 1.0000x reference)
//
#include <hip/hip_runtime.h>

// AmpLoss: 10 global reductions (5 mask counts + 5 masked smape-sums) over
// B=2^24 fp32 samples, then an O(1) sequential finalize.
// Memory-bound: reads exactly 4 arrays (dbp_pred, sbp_pred, d, s) = 256 MiB.

#define B_TOTAL 16777216
#define NSETS 8          // workspace slot-sets to spread atomic contention
#define NBLOCKS 2048
#define NTHREADS 256

__device__ __forceinline__ float smape_f(float p, float t) {
    return 2.0f * fabsf(p - t) / (fabsf(p) + fabsf(t));
}

__global__ __launch_bounds__(NTHREADS)
void amploss_reduce(const float* __restrict__ dbp,
                    const float* __restrict__ sbp,
                    const float* __restrict__ dt,
                    const float* __restrict__ st,
                    double* __restrict__ ws)
{
    double sum[5] = {0.0, 0.0, 0.0, 0.0, 0.0};
    int    cnt[5] = {0, 0, 0, 0, 0};

    const int nquads = B_TOTAL / 4;
    const int stride = gridDim.x * blockDim.x;
    const float4* __restrict__ dbp4 = (const float4*)dbp;
    const float4* __restrict__ sbp4 = (const float4*)sbp;
    const float4* __restrict__ dt4  = (const float4*)dt;
    const float4* __restrict__ st4  = (const float4*)st;

    for (int q = blockIdx.x * blockDim.x + threadIdx.x; q < nquads; q += stride) {
        float4 dp = dbp4[q];
        float4 sp = sbp4[q];
        float4 dv = dt4[q];
        float4 sv = st4[q];
        float dpv[4] = {dp.x, dp.y, dp.z, dp.w};
        float spv[4] = {sp.x, sp.y, sp.z, sp.w};
        float dvv[4] = {dv.x, dv.y, dv.z, dv.w};
        float svv[4] = {sv.x, sv.y, sv.z, sv.w};
        #pragma unroll
        for (int j = 0; j < 4; ++j) {
            float s = svv[j], d = dvv[j];
            bool normal   = (s < 120.0f) && (d < 80.0f);
            bool elevated = (s >= 120.0f) && (s < 130.0f) && (d < 80.0f) && !normal;
            bool h1 = (((s >= 130.0f) && (s < 140.0f)) || ((d >= 80.0f) && (d < 90.0f)))
                      && !(normal || elevated);
            bool h2 = ((s >= 140.0f) || (d >= 90.0f)) && !(normal || elevated || h1);
            bool crisis = (s > 180.0f) || (d > 120.0f);

            float pe = smape_f(dpv[j], d) + smape_f(spv[j], s);
            double ped = (double)pe;

            if (normal)   { cnt[0]++; sum[0] += ped; }
            if (elevated) { cnt[1]++; sum[1] += ped; }
            if (h1)       { cnt[2]++; sum[2] += ped; }
            if (h2)       { cnt[3]++; sum[3] += ped; }
            if (crisis)   { cnt[4]++; sum[4] += ped; }
        }
    }

    // wave-level butterfly reduce (wave = 64 lanes)
    #pragma unroll
    for (int off = 32; off > 0; off >>= 1) {
        #pragma unroll
        for (int k = 0; k < 5; ++k) {
            sum[k] += __shfl_down(sum[k], off);
            cnt[k] += __shfl_down(cnt[k], off);
        }
    }

    __shared__ double s_sum[5][NTHREADS / 64];
    __shared__ int    s_cnt[5][NTHREADS / 64];
    const int lane = threadIdx.x & 63;
    const int wid  = threadIdx.x >> 6;
    if (lane == 0) {
        #pragma unroll
        for (int k = 0; k < 5; ++k) { s_sum[k][wid] = sum[k]; s_cnt[k][wid] = cnt[k]; }
    }
    __syncthreads();

    if (threadIdx.x == 0) {
        const int base = (blockIdx.x & (NSETS - 1)) * 10;
        #pragma unroll
        for (int k = 0; k < 5; ++k) {
            double ss = 0.0; double cc = 0.0;
            #pragma unroll
            for (int w = 0; w < NTHREADS / 64; ++w) { ss += s_sum[k][w]; cc += (double)s_cnt[k][w]; }
            atomicAdd(&ws[base + k], ss);
            atomicAdd(&ws[base + 5 + k], cc);
        }
    }
}

__global__ void amploss_finalize(const double* __restrict__ ws, float* __restrict__ out)
{
    if (threadIdx.x != 0 || blockIdx.x != 0) return;
    double S[5], C[5];
    for (int k = 0; k < 5; ++k) { S[k] = 0.0; C[k] = 0.0; }
    for (int st = 0; st < NSETS; ++st)
        for (int k = 0; k < 5; ++k) {
            S[k] += ws[st * 10 + k];
            C[k] += ws[st * 10 + 5 + k];
        }

    double rst = 0.0, m_rst = 0.0, mask_cnt = 0.0;
    for (int k = 0; k < 5; ++k) {
        double c = C[k];
        // match reference's fp32 weight: sqrt(log(batchN / max(cnt,1)))
        float w = sqrtf(logf((float)B_TOTAL / fmaxf((float)c, 1.0f)));
        double Sw = S[k] * (double)w;
        if (c > 0.0) {
            m_rst = (m_rst + Sw) / c / 2.0;
            rst += m_rst;
            mask_cnt += 1.0;
        }
    }
    double r = (mask_cnt == 0.0) ? (rst / 5.0) : (rst / mask_cnt);
    out[0] = (float)r;
}

extern "C" void kernel_launch(void* const* d_in, const int* in_sizes, int n_in,
                              void* d_out, int out_size, void* d_ws, size_t ws_size,
                              hipStream_t stream) {
    // setup_inputs order: dbp_pred, sbp_pred, mbp_pred(unused), d, s, m(unused)
    const float* dbp = (const float*)d_in[0];
    const float* sbp = (const float*)d_in[1];
    const float* dt  = (const float*)d_in[3];
    const float* st  = (const float*)d_in[4];
    float* out = (float*)d_out;
    double* ws = (double*)d_ws;

    hipMemsetAsync(ws, 0, NSETS * 10 * sizeof(double), stream);
    amploss_reduce<<<NBLOCKS, NTHREADS, 0, stream>>>(dbp, sbp, dt, st, ws);
    amploss_finalize<<<1, 64, 0, stream>>>(ws, out);
}